// Round 7
// baseline (167.444 us; speedup 1.0000x reference)
//
#include <hip/hip_runtime.h>
#include <hip/hip_fp16.h>
#include <stdint.h>

// ---------------------------------------------------------------------------
// ThreeBodyLayer fused kernel v13 (MI355X / gfx950)
//
// All-f16 MFMA pipeline, log2-domain softplus. Scale algebra: W1/b1 carry
// log2(e); W2 carries ln2*log2(e)=1; b2*L2E; W3*LN2.
//
// v13 vs v12 (49us: 128-reg cap + sched_barrier walls halved occupancy) and
// v10 (42-44us, VGPR=32, ~50% issue-idle from per-wave serialized loads):
//  - Pipelining WITHIN the 64-reg cap (launch_bounds(1024,8) kept, so the
//    78KB-LDS 2-blocks/CU = 32 waves/CU occupancy is untouched):
//      * phase-2: k0-half cross-unit prefetch (8 regs) with named P/Q sets,
//        fully unrolled 4 units, loads textually first in each body, NO
//        sched_barrier walls (graceful degradation if allocator sinks).
//      * phase-1: all 8 W1T ds_read_b128 per slab hoisted ahead of the
//        MFMA/pack chain (v10 issued them just-in-time inside the nt loop).
//  - Everything else bit-identical to v10: ws prep (fill is sunk cost),
//    pre-swizzled W1T image + uint4 staging copy, operand-swapped phase-1
//    MFMA + packed b64 C-writes + b1-in-C-init, W2/b2/w3 from ws,
//    du0/du1 hoist, b2-in-C-init, T chunk-swizzle, RNE converts.
// ---------------------------------------------------------------------------

typedef __attribute__((ext_vector_type(8))) _Float16 f16x8;
typedef __attribute__((ext_vector_type(2))) __fp16   fp16v2;   // cvt_pkrtz ret
typedef __attribute__((ext_vector_type(4))) float    f32x4;
typedef __attribute__((ext_vector_type(4))) unsigned int u32x4;

constexpr int   BPB       = 32;       // batch elems per block
constexpr int   NT        = 1024;     // 16 waves
constexpr int   T_STRIDE  = 1664;     // 13 rows * 128 B, chunk-swizzled
constexpr int   WT_OFF    = BPB * T_STRIDE;       // 53248
constexpr int   Y_OFF     = WT_OFF + 192 * 128;   // 77824
constexpr int   LDS_BYTES = Y_OFF + 128;          // 77952 -> 2 blocks/CU

// d_ws layout (bytes)
constexpr int   WS_W1T   = 0;         // 24576: f16 LDS image (pre-swizzled)
constexpr int   WS_W2T   = 24576;     //  4096: f16 [m=32][k=64]
constexpr int   WS_B1    = 28672;     //   256: f32 b1*L2E
constexpr int   WS_B2    = 28928;     //   128: f32 b2*L2E
constexpr int   WS_W3    = 29056;     //   128: f32 W3*LN2

constexpr float L2E = 1.4426950408889634f;
constexpr float LN2 = 0.6931471805599453f;

// PAIRS i/j packed 3 bits per pair (15 pairs)
constexpr unsigned long long I_BITS =
  (0ull<<0)|(0ull<<3)|(0ull<<6)|(0ull<<9)|(0ull<<12)|
  (1ull<<15)|(1ull<<18)|(1ull<<21)|(1ull<<24)|
  (2ull<<27)|(2ull<<30)|(2ull<<33)|
  (3ull<<36)|(3ull<<39)|(4ull<<42);
constexpr unsigned long long J_BITS =
  (1ull<<0)|(2ull<<3)|(3ull<<6)|(4ull<<9)|(5ull<<12)|
  (2ull<<15)|(3ull<<18)|(4ull<<21)|(5ull<<24)|
  (3ull<<27)|(4ull<<30)|(5ull<<33)|
  (4ull<<36)|(5ull<<39)|(5ull<<42);

__device__ __forceinline__ float sp2(float s) {       // log2(1+exp2(s))
  float t = __builtin_amdgcn_exp2f(s);
  return __builtin_amdgcn_logf(1.0f + t);             // v_log_f32 = log2
}

__device__ __forceinline__ __half2 h1pair(__half2 u, __half2 a, __half2 b,
                                          __half2 one2) {
  __half2 s = __hadd2(__hadd2(u, a), b);
  __half2 t = h2exp2(s);                              // |s|<~8 -> safe in f16
  return h2log2(__hadd2(one2, t));
}

// ------------------------- prep: weights -> d_ws ---------------------------
__global__ __launch_bounds__(256)
void prep(const float* __restrict__ W1, const float* __restrict__ b1,
          const float* __restrict__ W2, const float* __restrict__ b2,
          const float* __restrict__ W3, char* __restrict__ ws)
{
  const int t = (int)(blockIdx.x * blockDim.x + threadIdx.x);   // 0..14591
  if (t < 12288) {
    // W1T LDS image: row r = slab*64+n (128B), logical d-chunk dc stored at
    // chunk dc^(r&7); element (r, dl): dg = slab*64+dl, value W1[dg][n]*L2E.
    const int r = t >> 6, dl = t & 63;
    const int slab = r >> 6, n = r & 63;
    const int dg = slab * 64 + dl;
    const float v = W1[(size_t)dg * 64 + n] * L2E;
    *(uint16_t*)(ws + WS_W1T + r * 128 + (((dl >> 3) ^ (r & 7)) << 4)
                 + (dl & 7) * 2) = __half_as_ushort(__float2half(v));
  } else if (t < 14336) {
    const int e = t - 12288;                          // W2 is [k=64][m=32]
    const int k = e >> 5, m = e & 31;
    *(uint16_t*)(ws + WS_W2T + (m * 64 + k) * 2) =
        __half_as_ushort(__float2half(W2[e]));
  } else if (t < 14400) {
    ((float*)(ws + WS_B1))[t - 14336] = b1[t - 14336] * L2E;
  } else if (t < 14432) {
    ((float*)(ws + WS_B2))[t - 14400] = b2[t - 14400] * L2E;
  } else if (t < 14464) {
    ((float*)(ws + WS_W3))[t - 14432] = W3[t - 14432] * LN2;
  }
}

// ---------------- phase-1 macros (fully inline, named vars) ----------------
#define P1_NT(TROW_, NTI, WA, WB)                                            \
  {                                                                          \
    f32x4 c_;                                                                \
    if ((TROW_) == 0)                                                        \
      c_ = *(const f32x4*)(ws + WS_B1 + ((NTI) * 16 + qd * 4) * 4);          \
    else                                                                     \
      c_ = (f32x4){0.f, 0.f, 0.f, 0.f};                                      \
    c_ = __builtin_amdgcn_mfma_f32_16x16x32_f16(WA, Xf[0].v, c_, 0, 0, 0);   \
    c_ = __builtin_amdgcn_mfma_f32_16x16x32_f16(WB, Xf[1].v, c_, 0, 0, 0);   \
    union PK_ { uint2 u; __half2 h[2]; } pk_;                                \
    pk_.h[0] = __halves2half2(__float2half(c_[0]), __float2half(c_[1]));     \
    pk_.h[1] = __halves2half2(__float2half(c_[2]), __float2half(c_[3]));     \
    *(uint2*)(smem + (size_t)(mt * 16 + ln) * T_STRIDE + (TROW_) * 128       \
              + (((((NTI) << 1) + (qd >> 1)) ^ swz) << 4) + (qd & 1) * 8) =  \
        pk_.u;                                                               \
  }

// Hoist all 8 W1T frags for one slab, then run the 4 nt sub-jobs.
#define P1_SLAB(TROW_, SL_)                                                  \
  {                                                                          \
    const char* base_ = smem + WT_OFF + (size_t)((SL_) * 64 + ln) * 128;     \
    const int o0_ = ((qd ^ swz) << 4);                                       \
    const int o1_ = (((4 + qd) ^ swz) << 4);                                 \
    const f16x8 W00_ = *(const f16x8*)(base_ + 0 * 2048 + o0_);              \
    const f16x8 W01_ = *(const f16x8*)(base_ + 0 * 2048 + o1_);              \
    const f16x8 W10_ = *(const f16x8*)(base_ + 1 * 2048 + o0_);              \
    const f16x8 W11_ = *(const f16x8*)(base_ + 1 * 2048 + o1_);              \
    const f16x8 W20_ = *(const f16x8*)(base_ + 2 * 2048 + o0_);              \
    const f16x8 W21_ = *(const f16x8*)(base_ + 2 * 2048 + o1_);              \
    const f16x8 W30_ = *(const f16x8*)(base_ + 3 * 2048 + o0_);              \
    const f16x8 W31_ = *(const f16x8*)(base_ + 3 * 2048 + o1_);              \
    P1_NT(TROW_, 0, W00_, W01_)                                              \
    P1_NT(TROW_, 1, W10_, W11_)                                              \
    P1_NT(TROW_, 2, W20_, W21_)                                              \
    P1_NT(TROW_, 3, W30_, W31_)                                              \
  }

// ---------------- phase-2 macros (named pipeline sets) ---------------------
#define PAIR_ADDR(Q_, TA_, TB_)                                              \
  {                                                                          \
    const int p_  = (Q_) >> 1;                                               \
    const int iv_ = (int)((I_BITS >> (3 * p_)) & 7ull);                      \
    const int jv_ = (int)((J_BITS >> (3 * p_)) & 7ull);                      \
    const int An_ = ((Q_) & 1) ? jv_ : iv_;                                  \
    const int Bn_ = ((Q_) & 1) ? iv_ : jv_;                                  \
    TA_ = Tb + (1 + An_) * 128;                                              \
    TB_ = Tb + (7 + Bn_) * 128;                                              \
  }

// One unit: k0 halves arrive prefetched in (C0a,C0b); k1 loads issue first,
// then (optionally) next unit's k0 prefetch into (N0a,N0b), then compute.
#define UNIT_BODY(TAc, TBc, C0a, C0b, PF, TAn, TBn, N0a, N0b)                \
  {                                                                          \
    U4 a1_, b1_;                                                             \
    a1_.u = *(const u32x4*)((TAc) + k1);                                     \
    b1_.u = *(const u32x4*)((TBc) + k1);                                     \
    if (PF) {                                                                \
      N0a.u = *(const u32x4*)((TAn) + k0);                                   \
      N0b.u = *(const u32x4*)((TBn) + k0);                                   \
    }                                                                        \
    union AH_ { f16x8 v; __half2 h[4]; } A0_, A1_;                           \
    A0_.h[0] = h1pair(du0.h[0], C0a.h[0], C0b.h[0], one2);                   \
    A0_.h[1] = h1pair(du0.h[1], C0a.h[1], C0b.h[1], one2);                   \
    A0_.h[2] = h1pair(du0.h[2], C0a.h[2], C0b.h[2], one2);                   \
    A0_.h[3] = h1pair(du0.h[3], C0a.h[3], C0b.h[3], one2);                   \
    A1_.h[0] = h1pair(du1.h[0], a1_.h[0], b1_.h[0], one2);                   \
    A1_.h[1] = h1pair(du1.h[1], a1_.h[1], b1_.h[1], one2);                   \
    A1_.h[2] = h1pair(du1.h[2], a1_.h[2], b1_.h[2], one2);                   \
    A1_.h[3] = h1pair(du1.h[3], a1_.h[3], b1_.h[3], one2);                   \
    f32x4 c0_ = {b2v0, b2v0, b2v0, b2v0};                                    \
    f32x4 c1_ = {b2v1, b2v1, b2v1, b2v1};                                    \
    c0_ = __builtin_amdgcn_mfma_f32_16x16x32_f16(A0_.v, W2f[0][0], c0_, 0, 0, 0); \
    c0_ = __builtin_amdgcn_mfma_f32_16x16x32_f16(A1_.v, W2f[0][1], c0_, 0, 0, 0); \
    c1_ = __builtin_amdgcn_mfma_f32_16x16x32_f16(A0_.v, W2f[1][0], c1_, 0, 0, 0); \
    c1_ = __builtin_amdgcn_mfma_f32_16x16x32_f16(A1_.v, W2f[1][1], c1_, 0, 0, 0); \
    yacc0 += sp2(c0_[0]) * w3v0 + sp2(c1_[0]) * w3v1;                        \
    yacc1 += sp2(c0_[1]) * w3v0 + sp2(c1_[1]) * w3v1;                        \
    yacc2 += sp2(c0_[2]) * w3v0 + sp2(c1_[2]) * w3v1;                        \
    yacc3 += sp2(c0_[3]) * w3v0 + sp2(c1_[3]) * w3v1;                        \
  }

// ------------------------------ main kernel --------------------------------
__global__ __launch_bounds__(NT, 8)
void tb_fused(const float* __restrict__ core, const float* __restrict__ ligs,
              const char* __restrict__ ws,   const float* __restrict__ b3,
              float* __restrict__ out)
{
  extern __shared__ char smem[];
  const int tid  = (int)threadIdx.x;
  const int lane = tid & 63;
  const int ln   = lane & 15;        // fragment column
  const int qd   = lane >> 4;        // fragment quad
  const int swz  = ln & 7;           // XOR chunk swizzle key
  const int wv   = __builtin_amdgcn_readfirstlane(tid >> 6);  // 0..15
  const int b0   = (int)blockIdx.x * BPB;

  float* yred = (float*)(smem + Y_OFF);

  // ---- Phase-1 x-tile prefetch (cold HBM): issue before LDS staging ------
  const int xr = wv >> 1;
  const int mt = wv & 1;
  float4 fA[4];
  if (wv < 14) {
    const float* src = (xr == 0)
        ? (core + (size_t)(b0 + mt * 16 + ln) * 64)
        : (ligs + ((size_t)(b0 + mt * 16 + ln) * 6 + (size_t)(xr - 1)) * 64);
    #pragma unroll
    for (int ks = 0; ks < 2; ++ks) {
      fA[ks * 2 + 0] = *(const float4*)(src + ks * 32 + qd * 8);
      fA[ks * 2 + 1] = *(const float4*)(src + ks * 32 + qd * 8 + 4);
    }
  }

  // ---- stage W1T: plain vector copy of the pre-swizzled f16 image --------
  {
    const uint4* src = (const uint4*)(ws + WS_W1T);   // 1536 chunks of 16B
    uint4*       dst = (uint4*)(smem + WT_OFF);
    dst[tid] = src[tid];
    if (tid < 512) dst[1024 + tid] = src[1024 + tid];
  }
  if (tid < BPB) yred[tid] = 0.0f;
  __syncthreads();                                    // barrier #1: W1T ready

  // ------------- Phase 1: 14 jobs = (xr 0..6) x (mt 0..1), 1 per wave -----
  if (wv < 14) {
    union AFr { f16x8 v; fp16v2 p[4]; } Xf[2];        // x frags (B operand)
    #pragma unroll
    for (int ks = 0; ks < 2; ++ks) {
      Xf[ks].p[0] = __builtin_amdgcn_cvt_pkrtz(fA[ks*2].x, fA[ks*2].y);
      Xf[ks].p[1] = __builtin_amdgcn_cvt_pkrtz(fA[ks*2].z, fA[ks*2].w);
      Xf[ks].p[2] = __builtin_amdgcn_cvt_pkrtz(fA[ks*2+1].x, fA[ks*2+1].y);
      Xf[ks].p[3] = __builtin_amdgcn_cvt_pkrtz(fA[ks*2+1].z, fA[ks*2+1].w);
    }

    if (xr == 0) {
      P1_SLAB(0, 0)
    } else {
      P1_SLAB(xr, 1)
      P1_SLAB(6 + xr, 2)
    }
  }

  // W2 B-frags + epilogue consts from ws (pre-converted, L2-hot) —
  // overlaps Phase-1 tail.
  f16x8 W2f[2][2];
  #pragma unroll
  for (int nt = 0; nt < 2; ++nt)
    #pragma unroll
    for (int ks = 0; ks < 2; ++ks)
      W2f[nt][ks] = *(const f16x8*)(ws + WS_W2T
          + ((nt * 16 + ln) * 64 + ks * 32 + qd * 8) * 2);
  const float b2v0 = ((const float*)(ws + WS_B2))[ln];
  const float b2v1 = ((const float*)(ws + WS_B2))[16 + ln];
  const float w3v0 = ((const float*)(ws + WS_W3))[ln];
  const float w3v1 = ((const float*)(ws + WS_W3))[16 + ln];

  __syncthreads();                                    // barrier #2: T ready

  // ------------- Phase 2: 60 units (30 q x 2 mt) over 16 waves ------------
  const int mtw = wv & 1;
  const int qr  = wv >> 1;                            // 0..7
  const __half2 one2 = __float2half2_rn(1.0f);
  const char* Tb = smem + (size_t)(mtw * 16 + ln) * T_STRIDE;
  const int k0 = ((qd)     ^ swz) << 4;               // chunk qd   (ks=0)
  const int k1 = ((qd + 4) ^ swz) << 4;               // chunk qd+4 (ks=1)

  union U4 { u32x4 u; __half2 h[4]; };

  // Row 0 (core pre-activations) is unit-invariant: hoist its 2 reads.
  U4 du0, du1;
  du0.u = *(const u32x4*)(Tb + k0);
  du1.u = *(const u32x4*)(Tb + k1);

  float yacc0 = 0.f, yacc1 = 0.f, yacc2 = 0.f, yacc3 = 0.f;

  const char *TA0, *TB0, *TA1, *TB1, *TA2, *TB2;
  const char *TA3 = Tb, *TB3 = Tb;
  PAIR_ADDR(qr,      TA0, TB0)
  PAIR_ADDR(qr + 8,  TA1, TB1)
  PAIR_ADDR(qr + 16, TA2, TB2)
  const bool has3 = (qr < 6);                         // wave-uniform
  if (has3) { PAIR_ADDR(qr + 24, TA3, TB3) }

  U4 P0a, P0b, Q0a, Q0b;                              // k0 pipeline sets
  P0a.u = *(const u32x4*)(TA0 + k0);                  // preload unit-0 k0
  P0b.u = *(const u32x4*)(TB0 + k0);

  UNIT_BODY(TA0, TB0, P0a, P0b, true,  TA1, TB1, Q0a, Q0b)   // unit qr
  UNIT_BODY(TA1, TB1, Q0a, Q0b, true,  TA2, TB2, P0a, P0b)   // unit qr+8
  UNIT_BODY(TA2, TB2, P0a, P0b, has3,  TA3, TB3, Q0a, Q0b)   // unit qr+16
  if (has3) {
    UNIT_BODY(TA3, TB3, Q0a, Q0b, false, Tb, Tb, P0a, P0b)   // unit qr+24
  }

  // reduce over the 16 fragment columns (ln) inside each quad group
  float v0 = yacc0, v1 = yacc1, v2 = yacc2, v3 = yacc3;
  v0 += __shfl_xor(v0, 1); v1 += __shfl_xor(v1, 1);
  v2 += __shfl_xor(v2, 1); v3 += __shfl_xor(v3, 1);
  v0 += __shfl_xor(v0, 2); v1 += __shfl_xor(v1, 2);
  v2 += __shfl_xor(v2, 2); v3 += __shfl_xor(v3, 2);
  v0 += __shfl_xor(v0, 4); v1 += __shfl_xor(v1, 4);
  v2 += __shfl_xor(v2, 4); v3 += __shfl_xor(v3, 4);
  v0 += __shfl_xor(v0, 8); v1 += __shfl_xor(v1, 8);
  v2 += __shfl_xor(v2, 8); v3 += __shfl_xor(v3, 8);
  if (ln == 0) {
    atomicAdd(&yred[mtw * 16 + qd * 4 + 0], v0);
    atomicAdd(&yred[mtw * 16 + qd * 4 + 1], v1);
    atomicAdd(&yred[mtw * 16 + qd * 4 + 2], v2);
    atomicAdd(&yred[mtw * 16 + qd * 4 + 3], v3);
  }
  __syncthreads();
  if (tid < BPB) out[b0 + tid] = 0.5f * yred[tid] + 15.0f * b3[0];
}

extern "C" void kernel_launch(void* const* d_in, const int* in_sizes, int n_in,
                              void* d_out, int out_size, void* d_ws, size_t ws_size,
                              hipStream_t stream) {
  const float* core = (const float*)d_in[0];
  const float* ligs = (const float*)d_in[1];
  const float* W1   = (const float*)d_in[2];
  const float* b1   = (const float*)d_in[3];
  const float* W2   = (const float*)d_in[4];
  const float* b2   = (const float*)d_in[5];
  const float* W3   = (const float*)d_in[6];
  const float* b3   = (const float*)d_in[7];
  float* out = (float*)d_out;
  char*  ws  = (char*)d_ws;                 // 29 KB used; fill is sunk cost

  const int B = in_sizes[0] / 64;           // 32768
  const int grid = B / BPB;                 // 1024

  prep<<<dim3(57), dim3(256), 0, stream>>>(W1, b1, W2, b2, W3, ws);

  (void)hipFuncSetAttribute((const void*)tb_fused,
                            hipFuncAttributeMaxDynamicSharedMemorySize, LDS_BYTES);
  tb_fused<<<dim3(grid), dim3(NT), LDS_BYTES, stream>>>(
      core, ligs, ws, b3, out);
}

// Round 8
// 126.762 us; speedup vs baseline: 1.3209x; 1.3209x over previous
//
#include <hip/hip_runtime.h>
#include <hip/hip_fp16.h>
#include <stdint.h>

// ---------------------------------------------------------------------------
// ThreeBodyLayer fused kernel v14 (MI355X / gfx950)
//
// All-f16 MFMA pipeline, log2-domain softplus. Scale algebra: W1/b1 carry
// log2(e); W2 carries ln2*log2(e)=1; b2*L2E; W3*LN2.
//
// v14 = v10 (best measured: 42.0-43.8us) + three isolated low-risk cuts:
//  - atomic-free reduction: per-wave f32x4 partials to a 16x32 LDS slab
//    (one ds_write_b128 per quad-leader) + 8-way sum by 32 threads.
//    Replaces 1024 LDS atomicAdd lane-ops at the convergent kernel tail.
//  - s_setprio(1) around phase-2: with 2 co-resident blocks, phase-2
//    MFMA/trans waves preempt the other block's staging waves (T5 regime).
//  - yred zeroing dropped (obsoleted).
//
// CLOSED LINES (measured, do not retry):
//  - Explicit phase-2 pipelining: v8/v13 (cross-region unions -> SROA fail
//    -> scratch at 64-reg cap), v12 (128-reg cap -> occupancy collapse).
//  - Occupancy reshaping: v9/v11 (24 waves/CU or 4x8-wave blocks: no gain).
//  - f16 epilogue + fdot2: absmax already at 0.015625; f16 ulp at |s|~15
//    is 0.0078 -> numerics risk.
//  - ws re-poison fill (256MiB, ~2x43us of dur_us) is unconditional (v7).
// ---------------------------------------------------------------------------

typedef __attribute__((ext_vector_type(8))) _Float16 f16x8;
typedef __attribute__((ext_vector_type(2))) __fp16   fp16v2;   // cvt_pkrtz ret
typedef __attribute__((ext_vector_type(4))) float    f32x4;
typedef __attribute__((ext_vector_type(4))) unsigned int u32x4;

constexpr int   BPB       = 32;       // batch elems per block
constexpr int   NT        = 1024;     // 16 waves
constexpr int   T_STRIDE  = 1664;     // 13 rows * 128 B, chunk-swizzled
constexpr int   WT_OFF    = BPB * T_STRIDE;       // 53248
constexpr int   YP_OFF    = WT_OFF + 192 * 128;   // 77824: 16x32 f32 partials
constexpr int   LDS_BYTES = YP_OFF + 2048;        // 79872 -> 2 blocks/CU

// d_ws layout (bytes)
constexpr int   WS_W1T   = 0;         // 24576: f16 LDS image (pre-swizzled)
constexpr int   WS_W2T   = 24576;     //  4096: f16 [m=32][k=64]
constexpr int   WS_B1    = 28672;     //   256: f32 b1*L2E
constexpr int   WS_B2    = 28928;     //   128: f32 b2*L2E
constexpr int   WS_W3    = 29056;     //   128: f32 W3*LN2

constexpr float L2E = 1.4426950408889634f;
constexpr float LN2 = 0.6931471805599453f;

// PAIRS i/j packed 3 bits per pair (15 pairs)
constexpr unsigned long long I_BITS =
  (0ull<<0)|(0ull<<3)|(0ull<<6)|(0ull<<9)|(0ull<<12)|
  (1ull<<15)|(1ull<<18)|(1ull<<21)|(1ull<<24)|
  (2ull<<27)|(2ull<<30)|(2ull<<33)|
  (3ull<<36)|(3ull<<39)|(4ull<<42);
constexpr unsigned long long J_BITS =
  (1ull<<0)|(2ull<<3)|(3ull<<6)|(4ull<<9)|(5ull<<12)|
  (2ull<<15)|(3ull<<18)|(4ull<<21)|(5ull<<24)|
  (3ull<<27)|(4ull<<30)|(5ull<<33)|
  (4ull<<36)|(5ull<<39)|(5ull<<42);

__device__ __forceinline__ float sp2(float s) {       // log2(1+exp2(s))
  float t = __builtin_amdgcn_exp2f(s);
  return __builtin_amdgcn_logf(1.0f + t);             // v_log_f32 = log2
}

__device__ __forceinline__ __half2 h1pair(__half2 u, __half2 a, __half2 b,
                                          __half2 one2) {
  __half2 s = __hadd2(__hadd2(u, a), b);
  __half2 t = h2exp2(s);                              // |s|<~8 -> safe in f16
  return h2log2(__hadd2(one2, t));
}

// ------------------------- prep: weights -> d_ws ---------------------------
__global__ __launch_bounds__(256)
void prep(const float* __restrict__ W1, const float* __restrict__ b1,
          const float* __restrict__ W2, const float* __restrict__ b2,
          const float* __restrict__ W3, char* __restrict__ ws)
{
  const int t = (int)(blockIdx.x * blockDim.x + threadIdx.x);   // 0..14591
  if (t < 12288) {
    // W1T LDS image: row r = slab*64+n (128B), logical d-chunk dc stored at
    // chunk dc^(r&7); element (r, dl): dg = slab*64+dl, value W1[dg][n]*L2E.
    const int r = t >> 6, dl = t & 63;
    const int slab = r >> 6, n = r & 63;
    const int dg = slab * 64 + dl;
    const float v = W1[(size_t)dg * 64 + n] * L2E;
    *(uint16_t*)(ws + WS_W1T + r * 128 + (((dl >> 3) ^ (r & 7)) << 4)
                 + (dl & 7) * 2) = __half_as_ushort(__float2half(v));
  } else if (t < 14336) {
    const int e = t - 12288;                          // W2 is [k=64][m=32]
    const int k = e >> 5, m = e & 31;
    *(uint16_t*)(ws + WS_W2T + (m * 64 + k) * 2) =
        __half_as_ushort(__float2half(W2[e]));
  } else if (t < 14400) {
    ((float*)(ws + WS_B1))[t - 14336] = b1[t - 14336] * L2E;
  } else if (t < 14432) {
    ((float*)(ws + WS_B2))[t - 14400] = b2[t - 14400] * L2E;
  } else if (t < 14464) {
    ((float*)(ws + WS_W3))[t - 14432] = W3[t - 14432] * LN2;
  }
}

// ------------------------------ main kernel --------------------------------
__global__ __launch_bounds__(NT, 8)
void tb_fused(const float* __restrict__ core, const float* __restrict__ ligs,
              const char* __restrict__ ws,   const float* __restrict__ b3,
              float* __restrict__ out)
{
  extern __shared__ char smem[];
  const int tid  = (int)threadIdx.x;
  const int lane = tid & 63;
  const int ln   = lane & 15;        // fragment column
  const int qd   = lane >> 4;        // fragment quad
  const int swz  = ln & 7;           // XOR chunk swizzle key
  const int wv   = __builtin_amdgcn_readfirstlane(tid >> 6);  // 0..15
  const int b0   = (int)blockIdx.x * BPB;

  // ---- Phase-1 x-tile prefetch (cold HBM): issue before LDS staging ------
  const int xr = wv >> 1;
  const int mt = wv & 1;
  float4 fA[4];
  if (wv < 14) {
    const float* src = (xr == 0)
        ? (core + (size_t)(b0 + mt * 16 + ln) * 64)
        : (ligs + ((size_t)(b0 + mt * 16 + ln) * 6 + (size_t)(xr - 1)) * 64);
    #pragma unroll
    for (int ks = 0; ks < 2; ++ks) {
      fA[ks * 2 + 0] = *(const float4*)(src + ks * 32 + qd * 8);
      fA[ks * 2 + 1] = *(const float4*)(src + ks * 32 + qd * 8 + 4);
    }
  }

  // ---- stage W1T: plain vector copy of the pre-swizzled f16 image --------
  {
    const uint4* src = (const uint4*)(ws + WS_W1T);   // 1536 chunks of 16B
    uint4*       dst = (uint4*)(smem + WT_OFF);
    dst[tid] = src[tid];
    if (tid < 512) dst[1024 + tid] = src[1024 + tid];
  }
  __syncthreads();                                    // barrier #1: W1T ready

  // ------------- Phase 1: 14 jobs = (xr 0..6) x (mt 0..1), 1 per wave -----
  if (wv < 14) {
    union AFr { f16x8 v; fp16v2 p[4]; } Xf[2];        // x frags (B operand)
    #pragma unroll
    for (int ks = 0; ks < 2; ++ks) {
      Xf[ks].p[0] = __builtin_amdgcn_cvt_pkrtz(fA[ks*2].x, fA[ks*2].y);
      Xf[ks].p[1] = __builtin_amdgcn_cvt_pkrtz(fA[ks*2].z, fA[ks*2].w);
      Xf[ks].p[2] = __builtin_amdgcn_cvt_pkrtz(fA[ks*2+1].x, fA[ks*2+1].y);
      Xf[ks].p[3] = __builtin_amdgcn_cvt_pkrtz(fA[ks*2+1].z, fA[ks*2+1].w);
    }

    const int sl_lo = (xr == 0) ? 0 : 1;
    const int sl_hi = (xr == 0) ? 0 : 2;
    #pragma unroll 1
    for (int sl = sl_lo; sl <= sl_hi; ++sl) {
      const int trow = (xr == 0) ? 0 : ((sl == 1) ? xr : 6 + xr);
      #pragma unroll
      for (int nt = 0; nt < 4; ++nt) {
        // D row = n (H1), col = batch: bias b1 folds into C-init (t=0 only).
        f32x4 c;
        if (trow == 0) {
          c = *(const f32x4*)(ws + WS_B1 + (nt * 16 + qd * 4) * 4);
        } else {
          c = (f32x4){0.f, 0.f, 0.f, 0.f};
        }
        #pragma unroll
        for (int ks = 0; ks < 2; ++ks) {
          // A = W1T frag: row = sl*64+nt*16+ln (row&7 == swz), chunk ks*4+qd
          const f16x8 Wf = *(const f16x8*)(smem + WT_OFF
              + (sl * 64 + nt * 16 + ln) * 128 + ((((ks << 2) + qd) ^ swz) << 4));
          c = __builtin_amdgcn_mfma_f32_16x16x32_f16(Wf, Xf[ks].v, c, 0, 0, 0);
        }
        // c[0..3] = consecutive n = nt*16+qd*4+reg, batch b = mt*16+ln.
        // One b64 write: off = trow*128 + ((2nt+(qd>>1))^(b&7))*16 + (qd&1)*8
        union PK { uint2 u; __half2 h[2]; } pk;
        pk.h[0] = __halves2half2(__float2half(c[0]), __float2half(c[1]));
        pk.h[1] = __halves2half2(__float2half(c[2]), __float2half(c[3]));
        *(uint2*)(smem + (size_t)(mt * 16 + ln) * T_STRIDE + trow * 128
                  + ((((nt << 1) + (qd >> 1)) ^ swz) << 4) + (qd & 1) * 8) = pk.u;
      }
    }
  }

  // W2 B-frags + epilogue consts from ws (pre-converted, L2-hot) —
  // overlaps Phase-1 tail.
  f16x8 W2f[2][2];
  #pragma unroll
  for (int nt = 0; nt < 2; ++nt)
    #pragma unroll
    for (int ks = 0; ks < 2; ++ks)
      W2f[nt][ks] = *(const f16x8*)(ws + WS_W2T
          + ((nt * 16 + ln) * 64 + ks * 32 + qd * 8) * 2);
  float b2v[2], w3v[2];
  #pragma unroll
  for (int nt = 0; nt < 2; ++nt) {
    b2v[nt] = ((const float*)(ws + WS_B2))[nt * 16 + ln];
    w3v[nt] = ((const float*)(ws + WS_W3))[nt * 16 + ln];
  }

  __syncthreads();                                    // barrier #2: T ready

  // ------------- Phase 2: 60 units (30 q x 2 mt) over 16 waves ------------
  const int mtw = wv & 1;
  const int qr  = wv >> 1;                            // 0..7
  const __half2 one2 = __float2half2_rn(1.0f);
  const char* Tb = smem + (size_t)(mtw * 16 + ln) * T_STRIDE;
  const int k0 = ((qd)     ^ swz) << 4;               // chunk qd   (ks=0)
  const int k1 = ((qd + 4) ^ swz) << 4;               // chunk qd+4 (ks=1)

  union U4 { u32x4 u; __half2 h[4]; };

  // Row 0 (core pre-activations) is unit-invariant: hoist its 2 reads.
  U4 du0, du1;
  du0.u = *(const u32x4*)(Tb + k0);
  du1.u = *(const u32x4*)(Tb + k1);

  float yacc[4] = {0.f, 0.f, 0.f, 0.f};

  __builtin_amdgcn_s_setprio(1);                      // favor compute waves
  #pragma unroll 2
  for (int t3 = 0; t3 < 4; ++t3) {
    const int q = qr + 8 * t3;
    if (q >= 30) break;                               // wave-uniform
    const int p  = q >> 1;
    const int iv = (int)((I_BITS >> (3 * p)) & 7ull);
    const int jv = (int)((J_BITS >> (3 * p)) & 7ull);
    const int An = (q & 1) ? jv : iv;
    const int Bn = (q & 1) ? iv : jv;
    const char* TA = Tb + (1 + An) * 128;
    const char* TB = Tb + (7 + Bn) * 128;

    U4 da0, db0, da1, db1;
    da0.u = *(const u32x4*)(TA + k0);
    db0.u = *(const u32x4*)(TB + k0);
    da1.u = *(const u32x4*)(TA + k1);
    db1.u = *(const u32x4*)(TB + k1);

    union { f16x8 v; __half2 h[4]; } A0, A1;
    #pragma unroll
    for (int w = 0; w < 4; ++w) A0.h[w] = h1pair(du0.h[w], da0.h[w], db0.h[w], one2);
    #pragma unroll
    for (int w = 0; w < 4; ++w) A1.h[w] = h1pair(du1.h[w], da1.h[w], db1.h[w], one2);

    f32x4 c0 = {b2v[0], b2v[0], b2v[0], b2v[0]};      // bias as C-init
    f32x4 c1 = {b2v[1], b2v[1], b2v[1], b2v[1]};
    c0 = __builtin_amdgcn_mfma_f32_16x16x32_f16(A0.v, W2f[0][0], c0, 0, 0, 0);
    c0 = __builtin_amdgcn_mfma_f32_16x16x32_f16(A1.v, W2f[0][1], c0, 0, 0, 0);
    c1 = __builtin_amdgcn_mfma_f32_16x16x32_f16(A0.v, W2f[1][0], c1, 0, 0, 0);
    c1 = __builtin_amdgcn_mfma_f32_16x16x32_f16(A1.v, W2f[1][1], c1, 0, 0, 0);

    #pragma unroll
    for (int reg = 0; reg < 4; ++reg) {
      yacc[reg] += sp2(c0[reg]) * w3v[0] + sp2(c1[reg]) * w3v[1];
    }
  }
  __builtin_amdgcn_s_setprio(0);

  // reduce over the 16 fragment columns (ln) inside each quad group
  #pragma unroll
  for (int reg = 0; reg < 4; ++reg) {
    float v = yacc[reg];
    v += __shfl_xor(v, 1);
    v += __shfl_xor(v, 2);
    v += __shfl_xor(v, 4);
    v += __shfl_xor(v, 8);
    yacc[reg] = v;
  }
  // per-wave partial: one ds_write_b128 per quad leader (no atomics)
  if (ln == 0) {
    float* dst = (float*)(smem + YP_OFF) + (wv * 32 + mtw * 16 + qd * 4);
    *(f32x4*)dst = (f32x4){yacc[0], yacc[1], yacc[2], yacc[3]};
  }
  __syncthreads();
  if (tid < BPB) {
    const float* yp = (const float*)(smem + YP_OFF);
    const int mtb = tid >> 4;                         // which mt half
    float s = 0.f;
    #pragma unroll
    for (int k = 0; k < 8; ++k)
      s += yp[(2 * k + mtb) * 32 + tid];
    out[b0 + tid] = 0.5f * s + 15.0f * b3[0];
  }
}

extern "C" void kernel_launch(void* const* d_in, const int* in_sizes, int n_in,
                              void* d_out, int out_size, void* d_ws, size_t ws_size,
                              hipStream_t stream) {
  const float* core = (const float*)d_in[0];
  const float* ligs = (const float*)d_in[1];
  const float* W1   = (const float*)d_in[2];
  const float* b1   = (const float*)d_in[3];
  const float* W2   = (const float*)d_in[4];
  const float* b2   = (const float*)d_in[5];
  const float* W3   = (const float*)d_in[6];
  const float* b3   = (const float*)d_in[7];
  float* out = (float*)d_out;
  char*  ws  = (char*)d_ws;                 // 29 KB used; fill is sunk cost

  const int B = in_sizes[0] / 64;           // 32768
  const int grid = B / BPB;                 // 1024

  prep<<<dim3(57), dim3(256), 0, stream>>>(W1, b1, W2, b2, W3, ws);

  (void)hipFuncSetAttribute((const void*)tb_fused,
                            hipFuncAttributeMaxDynamicSharedMemorySize, LDS_BYTES);
  tb_fused<<<dim3(grid), dim3(NT), LDS_BYTES, stream>>>(
      core, ligs, ws, b3, out);
}